// Round 4
// baseline (284.730 us; speedup 1.0000x reference)
//
#include <hip/hip_runtime.h>

// Fused DropBlock + LIF forward, single kernel.
// x: [T*bs, C, H, W] = [160, 64, 64, 64] f32, mask_rand: [160, 64, 64] f32
// out: [160, 64, 64, 64] f32 (values are only 0.0 / 1.0 = spike * blockmask)
//
// Grid: 32 (b) x 32 (row-pair groups) = 1024 blocks, 256 threads.
// Stage A: per block, compute the 10 needed dropblock row-masks
//   (2 rows x 5 timesteps) as 64-bit masks: 7 clipped vertical loads/lane
//   -> OR -> __ballot (vertical dilate) -> bit smear +/-3 (horizontal dilate).
//   W=64 exactly matches the 64-bit ballot word; shifts clip at row edges.
// Stage B: LIF recurrence u_{t+1} = (u>1 ? 0 : 0.5u) + x_t (bitwise equal to
//   tau*u*(1-spike)+x), o_t = (u>1 && !dropped) ? 1 : 0. NT float4 streaming.

#define TSTEPS 5
#define BSZ 32
#define CHN 64
#define HH 64
#define WW 64

typedef float v4f __attribute__((ext_vector_type(4)));

__global__ __launch_bounds__(256) void fused_kernel(const float* __restrict__ x,
                                                    const float* __restrict__ mr,
                                                    float* __restrict__ o) {
    __shared__ unsigned long long bmbits[2 * TSTEPS];  // [t*2 + row_in_group]
    const float GAMMA = (float)(0.1 / 49.0);  // matches JAX weak-type promotion
    int b = blockIdx.x >> 5;
    int g = blockIdx.x & 31;  // row-pair group
    int r0 = g << 1;
    int tid = threadIdx.x;
    int wave = tid >> 6;
    int lane = tid & 63;

    // ---- Stage A: 10 row-masks, distributed over the block's 4 waves ----
    for (int m = wave; m < 2 * TSTEPS; m += 4) {  // wave-uniform iterations
        int row = r0 + (m & 1);
        int t = m >> 1;
        const float* base = mr + (size_t)(t * BSZ + b) * (HH * WW) + lane;
        bool drop = false;
#pragma unroll
        for (int dh = -3; dh <= 3; ++dh) {
            int hh = row + dh;
            if (hh >= 0 && hh < HH) drop = drop || (base[hh * WW] < GAMMA);
        }
        unsigned long long mm = __ballot(drop);  // bit w = column-dropped (vert done)
        unsigned long long s = mm | (mm << 1) | (mm << 2) | (mm << 3)
                                  | (mm >> 1) | (mm >> 2) | (mm >> 3);
        if (lane == 0) bmbits[m] = s;  // set bit => dropped => bm = 0
    }
    __syncthreads();

    // ---- Stage B: LIF stream ----
    int pos = tid & 31;       // float4 index within the 2-row strip
    int row_in = pos >> 4;    // 0/1
    int col4 = pos & 15;      // float4 column
    unsigned int nib[TSTEPS];
#pragma unroll
    for (int t = 0; t < TSTEPS; ++t)
        nib[t] = (unsigned int)((bmbits[t * 2 + row_in] >> (col4 * 4)) & 0xFull);

    int c0 = tid >> 5;  // 0..7
    const size_t XT = (size_t)BSZ * CHN * HH * WW;  // time stride in x/o
    size_t base_off = (size_t)b * CHN * (HH * WW)
                    + (size_t)(r0 + row_in) * WW + (size_t)col4 * 4;
    for (int c = c0; c < CHN; c += 8) {
        size_t xoff = base_off + (size_t)c * (HH * WW);
        v4f u = {0.f, 0.f, 0.f, 0.f};
#pragma unroll
        for (int t = 0; t < TSTEPS; ++t) {
            v4f xv = __builtin_nontemporal_load((const v4f*)(x + xoff + (size_t)t * XT));
            u.x = (u.x > 1.0f ? 0.0f : 0.5f * u.x) + xv.x;
            u.y = (u.y > 1.0f ? 0.0f : 0.5f * u.y) + xv.y;
            u.z = (u.z > 1.0f ? 0.0f : 0.5f * u.z) + xv.z;
            u.w = (u.w > 1.0f ? 0.0f : 0.5f * u.w) + xv.w;
            v4f ov;
            ov.x = (u.x > 1.0f && !(nib[t] & 1u)) ? 1.0f : 0.0f;
            ov.y = (u.y > 1.0f && !(nib[t] & 2u)) ? 1.0f : 0.0f;
            ov.z = (u.z > 1.0f && !(nib[t] & 4u)) ? 1.0f : 0.0f;
            ov.w = (u.w > 1.0f && !(nib[t] & 8u)) ? 1.0f : 0.0f;
            __builtin_nontemporal_store(ov, (v4f*)(o + xoff + (size_t)t * XT));
        }
    }
}

extern "C" void kernel_launch(void* const* d_in, const int* in_sizes, int n_in,
                              void* d_out, int out_size, void* d_ws, size_t ws_size,
                              hipStream_t stream) {
    const float* x = (const float*)d_in[0];
    const float* mask_rand = (const float*)d_in[1];
    float* out = (float*)d_out;
    (void)d_ws; (void)ws_size;

    const int nblocks = BSZ * (HH / 2);  // 32 b x 32 row-pair groups = 1024
    fused_kernel<<<nblocks, 256, 0, stream>>>(x, mask_rand, out);
}

// Round 5
// 278.074 us; speedup vs baseline: 1.0239x; 1.0239x over previous
//
#include <hip/hip_runtime.h>

// DropBlock + LIF forward, two kernels (R3 structure, bit-packed masks).
// x: [T*bs, C, H, W] = [160, 64, 64, 64] f32, mask_rand: [160, 64, 64] f32
// out: [160, 64, 64, 64] f32
//
// Stage 1 (bm_bits_kernel): per row (one wave each), dropblock row-mask as a
//   64-bit word: 7 clipped vertical loads/lane -> OR -> __ballot (vertical
//   dilate) -> bit smear +/-3 (horizontal dilate). Set bit = dropped.
//   Output: 10240 x uint64 = 80 KB in d_ws (L1/L2-resident for stage 2).
// Stage 2 (lif_kernel): linear-index float4 streaming (proven best locality):
//   u = (u>1 ? 0 : 0.5u) + x_t (bitwise equal to tau*u*(1-spike)+x),
//   o_t = (u>1 && !dropped) ? 1 : 0. NT loads/stores on x/o; per-t mask is
//   one 8 B load (4 distinct addresses per wave -> broadcast, cache-hot).

#define TSTEPS 5
#define BSZ 32
#define CHN 64
#define HH 64
#define WW 64

typedef float v4f __attribute__((ext_vector_type(4)));

__global__ __launch_bounds__(256) void bm_bits_kernel(const float* __restrict__ mr,
                                                      unsigned long long* __restrict__ bmbits) {
    // one wave (64 lanes) per row; 4 waves per block; rows = T*bs*HH = 10240
    const float GAMMA = (float)(0.1 / 49.0);  // matches JAX weak-type promotion
    int row = blockIdx.x * 4 + (threadIdx.x >> 6);  // [0, 10240)
    int lane = threadIdx.x & 63;                    // pixel w
    int h = row & (HH - 1);
    int n = row >> 6;  // plane id in [0, T*bs)

    const float* base = mr + (size_t)n * (HH * WW) + lane;
    bool drop = false;
#pragma unroll
    for (int dh = -3; dh <= 3; ++dh) {
        int hh = h + dh;
        if (hh >= 0 && hh < HH) drop = drop || (base[hh * WW] < GAMMA);
    }
    unsigned long long m = __ballot(drop);  // bit w = column drop (vertical done)
    unsigned long long s = m | (m << 1) | (m << 2) | (m << 3)
                             | (m >> 1) | (m >> 2) | (m >> 3);
    if (lane == 0) bmbits[row] = s;  // set bit => dropped => output 0
}

__global__ __launch_bounds__(256) void lif_kernel(const float* __restrict__ x,
                                                  const unsigned long long* __restrict__ bmbits,
                                                  float* __restrict__ o) {
    const int HW4 = HH * WW / 4;  // 1024 float4 groups per plane
    int idx = blockIdx.x * blockDim.x + threadIdx.x;  // [0, BSZ*CHN*HW4)
    int hw4 = idx & (HW4 - 1);
    int c = (idx >> 10) & (CHN - 1);
    int b = idx >> 16;
    if (b >= BSZ) return;

    int h = hw4 >> 4;     // row within plane
    int col4 = hw4 & 15;  // float4 column
    int sh = col4 * 4;

    size_t xoff = (((size_t)b * CHN + c) * (size_t)(HH * WW)) + (size_t)hw4 * 4;
    const size_t XT = (size_t)BSZ * CHN * HH * WW;  // x/o time stride
    int mrow = b * HH + h;                          // + t*BSZ*HH per step
    const int MT = BSZ * HH;

    v4f u = {0.f, 0.f, 0.f, 0.f};
#pragma unroll
    for (int t = 0; t < TSTEPS; ++t) {
        v4f xv = __builtin_nontemporal_load((const v4f*)(x + xoff + (size_t)t * XT));
        unsigned int nib = (unsigned int)((bmbits[mrow + t * MT] >> sh) & 0xFull);
        u.x = (u.x > 1.0f ? 0.0f : 0.5f * u.x) + xv.x;
        u.y = (u.y > 1.0f ? 0.0f : 0.5f * u.y) + xv.y;
        u.z = (u.z > 1.0f ? 0.0f : 0.5f * u.z) + xv.z;
        u.w = (u.w > 1.0f ? 0.0f : 0.5f * u.w) + xv.w;
        v4f ov;
        ov.x = (u.x > 1.0f && !(nib & 1u)) ? 1.0f : 0.0f;
        ov.y = (u.y > 1.0f && !(nib & 2u)) ? 1.0f : 0.0f;
        ov.z = (u.z > 1.0f && !(nib & 4u)) ? 1.0f : 0.0f;
        ov.w = (u.w > 1.0f && !(nib & 8u)) ? 1.0f : 0.0f;
        __builtin_nontemporal_store(ov, (v4f*)(o + xoff + (size_t)t * XT));
    }
}

extern "C" void kernel_launch(void* const* d_in, const int* in_sizes, int n_in,
                              void* d_out, int out_size, void* d_ws, size_t ws_size,
                              hipStream_t stream) {
    const float* x = (const float*)d_in[0];
    const float* mask_rand = (const float*)d_in[1];
    float* out = (float*)d_out;
    unsigned long long* bmbits = (unsigned long long*)d_ws;  // 10240 * 8 B = 80 KB

    const int bm_rows = TSTEPS * BSZ * HH;              // 10240 rows (1 wave each)
    const int lif_threads = BSZ * CHN * (HH * WW / 4);  // 2,097,152

    bm_bits_kernel<<<bm_rows / 4, 256, 0, stream>>>(mask_rand, bmbits);
    lif_kernel<<<(lif_threads + 255) / 256, 256, 0, stream>>>(x, bmbits, out);
}